// Round 1
// baseline (285.777 us; speedup 1.0000x reference)
//
#include <hip/hip_runtime.h>
#include <stdint.h>

#define BATCH   32
#define ROWS    4096
#define COLS    256
#define COL_IDX 5

// ---------------------------------------------------------------------------
// Kernel 1: per-batch bitonic sort of (key,row) packed u64 in LDS.
// Descending by key, stable (ascending row index on ties):
//   ordered(f): monotonic float->uint map; complement it so ascending u64
//   sort == descending float sort; low 32 bits = row index (tie-break).
// ---------------------------------------------------------------------------
__global__ __launch_bounds__(1024)
void sort_keys_kernel(const float* __restrict__ x, int* __restrict__ idx_out) {
    __shared__ unsigned long long keys[ROWS];
    const int b = blockIdx.x;
    const float* xb = x + (size_t)b * ROWS * COLS;

    for (int i = threadIdx.x; i < ROWS; i += blockDim.x) {
        unsigned int u = __float_as_uint(xb[(size_t)i * COLS + COL_IDX]);
        u = (u >> 31) ? ~u : (u | 0x80000000u);  // order-preserving map
        u = ~u;                                   // descending
        keys[i] = ((unsigned long long)u << 32) | (unsigned int)i;
    }
    __syncthreads();

    for (int k = 2; k <= ROWS; k <<= 1) {
        for (int j = k >> 1; j > 0; j >>= 1) {
            for (int i = threadIdx.x; i < ROWS; i += blockDim.x) {
                int ixj = i ^ j;
                if (ixj > i) {
                    bool up = ((i & k) == 0);
                    unsigned long long a = keys[i];
                    unsigned long long c = keys[ixj];
                    if ((a > c) == up) { keys[i] = c; keys[ixj] = a; }
                }
            }
            __syncthreads();
        }
    }

    for (int i = threadIdx.x; i < ROWS; i += blockDim.x) {
        idx_out[b * ROWS + i] = (int)(keys[i] & 0xFFFFFFFFu);
    }
}

// ---------------------------------------------------------------------------
// Kernel 2: row gather. One wave (64 lanes) per output row; float4 per lane
// = 256 floats = one full row. 4 rows per 256-thread block.
// ---------------------------------------------------------------------------
__global__ __launch_bounds__(256)
void gather_rows_kernel(const float* __restrict__ x,
                        const int* __restrict__ idx,
                        float* __restrict__ out) {
    const int r    = blockIdx.x * 4 + (threadIdx.x >> 6);  // global output row
    const int lane = threadIdx.x & 63;
    const int b    = r >> 12;            // r / 4096
    const int src  = idx[r];             // wave-uniform broadcast load

    const float4* sp = (const float4*)(x   + ((size_t)b * ROWS + src) * COLS);
    float4*       dp = (float4*)      (out + (size_t)r * COLS);
    dp[lane] = sp[lane];
}

extern "C" void kernel_launch(void* const* d_in, const int* in_sizes, int n_in,
                              void* d_out, int out_size, void* d_ws, size_t ws_size,
                              hipStream_t stream) {
    const float* x   = (const float*)d_in[0];
    float*       out = (float*)d_out;
    int*         idx = (int*)d_ws;   // BATCH*ROWS*4 = 512 KB scratch

    sort_keys_kernel<<<BATCH, 1024, 0, stream>>>(x, idx);
    gather_rows_kernel<<<(BATCH * ROWS) / 4, 256, 0, stream>>>(x, idx, out);
}